// Round 5
// baseline (765.863 us; speedup 1.0000x reference)
//
#include <hip/hip_runtime.h>

#define T_TOK 4096
#define HDIM  1024
#define NEXP  8
#define FFDIM 4096
#define NPAIR 8192   // T_TOK * topk

typedef __attribute__((ext_vector_type(8))) short short8;
typedef __attribute__((ext_vector_type(8))) unsigned short ushort8;
typedef __attribute__((ext_vector_type(4))) float f32x4;

__device__ __forceinline__ unsigned short f2bf(float f) {
  unsigned int u = __float_as_uint(f);
  u += 0x7fffu + ((u >> 16) & 1u);   // RNE
  return (unsigned short)(u >> 16);
}

// global -> LDS direct copy, 16B per lane. LDS dest is wave-uniform base;
// HW writes lane l at base + l*16. Global source address is per-lane.
__device__ __forceinline__ void gload16(const void* g, const void* l) {
  __builtin_amdgcn_global_load_lds(
      (const __attribute__((address_space(1))) unsigned int*)(unsigned long long)g,
      (__attribute__((address_space(3))) unsigned int*)(unsigned int)(unsigned long long)l,
      16, 0, 0);
}

// ---------------- conversions ----------------

__global__ __launch_bounds__(256) void convert_x_kernel(
    const float* __restrict__ in, unsigned short* __restrict__ out) {
  int i = (blockIdx.x * 256 + threadIdx.x) * 8;
  float4 a = *(const float4*)(in + i);
  float4 b = *(const float4*)(in + i + 4);
  ushort8 o;
  o[0] = f2bf(a.x); o[1] = f2bf(a.y); o[2] = f2bf(a.z); o[3] = f2bf(a.w);
  o[4] = f2bf(b.x); o[5] = f2bf(b.y); o[6] = f2bf(b.z); o[7] = f2bf(b.w);
  *(ushort8*)(out + i) = o;
}

// [M][N] fp32 -> [N][M] bf16, per-expert (blockIdx.z), 64x64 tiles
__global__ __launch_bounds__(256) void transpose_bf16_kernel(
    const float* __restrict__ in, unsigned short* __restrict__ out, int M, int N) {
  in  += (size_t)blockIdx.z * M * N;
  out += (size_t)blockIdx.z * M * N;
  __shared__ unsigned short t[64][72];
  int tid = threadIdx.x;
  int r0 = blockIdx.y * 64, c0 = blockIdx.x * 64;
#pragma unroll
  for (int rr = 0; rr < 4; rr++) {
    int row = rr * 16 + (tid >> 4);
    int col = (tid & 15) * 4;
    float4 v = *(const float4*)(in + (size_t)(r0 + row) * N + c0 + col);
    t[col + 0][row] = f2bf(v.x);
    t[col + 1][row] = f2bf(v.y);
    t[col + 2][row] = f2bf(v.z);
    t[col + 3][row] = f2bf(v.w);
  }
  __syncthreads();
#pragma unroll
  for (int rr = 0; rr < 2; rr++) {
    int c = rr * 32 + (tid >> 3);
    int m0 = (tid & 7) * 8;
    ushort8 v = *(const ushort8*)&t[c][m0];
    *(ushort8*)(out + (size_t)(c0 + c) * M + r0 + m0) = v;
  }
}

// ---------------- router ----------------

__global__ __launch_bounds__(256) void router_kernel(
    const float* __restrict__ x, const float* __restrict__ wg,
    int* __restrict__ sel_e, float* __restrict__ sel_w, int* __restrict__ counts) {
  int lane = threadIdx.x & 63;
  int t = blockIdx.x * 4 + (threadIdx.x >> 6);
  const float* xr = x + (size_t)t * HDIM;
  float acc[8] = {0, 0, 0, 0, 0, 0, 0, 0};
  for (int i = 0; i < HDIM / 64; i++) {
    int h = i * 64 + lane;
    float xv = xr[h];
    float4 w0 = *(const float4*)(wg + h * 8);
    float4 w1 = *(const float4*)(wg + h * 8 + 4);
    acc[0] += xv * w0.x; acc[1] += xv * w0.y; acc[2] += xv * w0.z; acc[3] += xv * w0.w;
    acc[4] += xv * w1.x; acc[5] += xv * w1.y; acc[6] += xv * w1.z; acc[7] += xv * w1.w;
  }
#pragma unroll
  for (int off = 32; off > 0; off >>= 1) {
#pragma unroll
    for (int e = 0; e < 8; e++) acc[e] += __shfl_xor(acc[e], off, 64);
  }
  if (lane == 0) {
    int e0 = 0; float b0 = acc[0];
#pragma unroll
    for (int e = 1; e < 8; e++) if (acc[e] > b0) { b0 = acc[e]; e0 = e; }
    int e1 = -1; float b1 = -3.4e38f;
#pragma unroll
    for (int e = 0; e < 8; e++) if (e != e0 && acc[e] > b1) { b1 = acc[e]; e1 = e; }
    float q = expf(b1 - b0);                 // softmax denominator cancels in renorm
    float w0 = 1.0f / (1.0f + q);
    float w1 = q / (1.0f + q);
    sel_e[t * 2] = e0; sel_e[t * 2 + 1] = e1;
    sel_w[t * 2] = w0; sel_w[t * 2 + 1] = w1;
    atomicAdd(&counts[e0], 1);
    atomicAdd(&counts[e1], 1);
  }
}

__global__ void offsets_kernel(const int* __restrict__ counts,
                               int* __restrict__ offsets, int* __restrict__ cursor) {
  if (threadIdx.x == 0 && blockIdx.x == 0) {
    int s = 0;
    for (int e = 0; e < NEXP; e++) { offsets[e] = s; cursor[e] = s; s += counts[e]; }
  }
}

__global__ __launch_bounds__(256) void scatter_kernel(
    const int* __restrict__ sel_e, const float* __restrict__ sel_w,
    int* __restrict__ cursor, int* __restrict__ pair_token, float* __restrict__ pair_w) {
  int t = blockIdx.x * 256 + threadIdx.x;
#pragma unroll
  for (int j = 0; j < 2; j++) {
    int e = sel_e[t * 2 + j];
    int pos = atomicAdd(&cursor[e], 1);
    pair_token[pos] = t;
    pair_w[pos] = sel_w[t * 2 + j];
  }
}

// ------- expert GEMMs: m97 structure. 128x128 tile, BK=64, single 32KB LDS -------
// 4 waves (2M x 2N), wave tile 64x64, acc[4][4]. Per K-step: barrier; stage 8x
// gload16 (A 16KB + B 16KB); barrier (compiler drains vmcnt(0)); 16 ds_read_b128
// + 32 MFMA. 3 blocks/CU provide the TLP that covers the barrier drain (m114).
// Swizzle (octet rule): rows are 128B = 8 chunks of 16B; LDS chunk(row,c) holds
// global k-chunk c ^ (row&7). Each consecutive-8-lane octet of a ds_read_b128
// then covers 8 distinct 16B slots -> conflict-free (round-2/4 A/B evidence).
// Grid: (by, bx, e*KSPL), by fastest -> consecutive blocks share the B-panel
// (256-512KB, L2-resident) and stream the expert's A slice (~2-4MB, L2/L3).
template <int KD, int KSPL, bool GATHER, bool SQRELU>
__global__ __launch_bounds__(256, 3) void moe_gemm_kernel(
    const unsigned short* __restrict__ A0, const unsigned short* __restrict__ B0,
    const int* __restrict__ offsets, const int* __restrict__ counts,
    const int* __restrict__ pair_token, const float* __restrict__ pair_w,
    unsigned short* __restrict__ h1out, float* __restrict__ out) {
  constexpr int ND = SQRELU ? FFDIM : HDIM;
  constexpr int KLEN = KD / KSPL;
  constexpr int NSTEP = KLEN / 64;

  int by = blockIdx.x;             // M-tile (fastest -> B-panel L2 reuse)
  int bx = blockIdx.y;             // N-panel
  int e  = blockIdx.z / KSPL;
  int ks = blockIdx.z % KSPL;
  int segstart = offsets[e];
  int segcnt = counts[e];
  if (by * 128 >= segcnt) return;
  const unsigned short* B = B0 + (size_t)e * ND * KD + (size_t)ks * KLEN;
  const unsigned short* Abase = A0 + (size_t)ks * KLEN;

  int tid = threadIdx.x;
  int lane = tid & 63;
  int wv = tid >> 6;       // 0..3
  int wr = wv >> 1;        // 0..1  (M)
  int wc = wv & 1;         // 0..1  (N)
  int g  = lane >> 4;      // 0..3
  int lr = lane & 15;

  // staging: inst i stages rows i*32 + (tid>>3); source k-chunk pre-swizzled
  int srow = tid >> 3;               // 0..31
  int schunk = (tid & 7) ^ (srow & 7);
  const unsigned short* aP[4];
  const unsigned short* bP[4];
#pragma unroll
  for (int i = 0; i < 4; i++) {
    int arow = i * 32 + srow;
    int idx = by * 128 + arow;
    if (idx >= segcnt) idx = segcnt - 1;   // clamp pad rows
    int p = segstart + idx;
    size_t rowoff;
    if (GATHER) rowoff = (size_t)pair_token[p] * KD;
    else        rowoff = (size_t)p * KD;
    aP[i] = Abase + rowoff + schunk * 8;
    bP[i] = B + (size_t)(bx * 128 + arow) * KD + schunk * 8;
  }

  __shared__ char lds[32768];        // A: [0,16K), B: [16K,32K)
  const char* ldsc = lds;
  int ldsW = wv * 1024;              // wave-uniform (lane*16 added by HW)

  f32x4 acc[4][4];
#pragma unroll
  for (int i = 0; i < 4; i++)
#pragma unroll
    for (int j = 0; j < 4; j++) acc[i][j] = (f32x4){0.f, 0.f, 0.f, 0.f};

  for (int t = 0; t < NSTEP; ++t) {
    if (t) __syncthreads();          // WAR: previous step's reads complete
#pragma unroll
    for (int i = 0; i < 4; i++) gload16(aP[i], ldsc + i * 4096 + ldsW);
#pragma unroll
    for (int i = 0; i < 4; i++) gload16(bP[i], ldsc + 16384 + i * 4096 + ldsW);
#pragma unroll
    for (int i = 0; i < 4; i++) { aP[i] += 64; bP[i] += 64; }
    __syncthreads();                 // RAW: compiler emits vmcnt(0) drain here

    short8 af[2][4], bf[2][4];
#pragma unroll
    for (int kk = 0; kk < 2; kk++) {
      int swz = ((kk * 4 + g) ^ (lr & 7)) * 16;
#pragma unroll
      for (int mi = 0; mi < 4; mi++)
        af[kk][mi] = *(const short8*)(ldsc + (wr * 64 + mi * 16 + lr) * 128 + swz);
#pragma unroll
      for (int nj = 0; nj < 4; nj++)
        bf[kk][nj] = *(const short8*)(ldsc + 16384 + (wc * 64 + nj * 16 + lr) * 128 + swz);
    }
#pragma unroll
    for (int kk = 0; kk < 2; kk++)
#pragma unroll
      for (int mi = 0; mi < 4; mi++)
#pragma unroll
        for (int nj = 0; nj < 4; nj++)
          acc[mi][nj] = __builtin_amdgcn_mfma_f32_16x16x32_bf16(af[kk][mi], bf[kk][nj], acc[mi][nj], 0, 0, 0);
  }

  // ---- epilogue: C/D layout col=lane&15, row=(lane>>4)*4+q ----
  int colb = bx * 128 + wc * 64 + lr;      // + nj*16
  int rowb = by * 128 + wr * 64 + g * 4;   // + mi*16 + q
#pragma unroll
  for (int mi = 0; mi < 4; mi++) {
#pragma unroll
    for (int q = 0; q < 4; q++) {
      int idx = rowb + mi * 16 + q;
      if (idx < segcnt) {
        int p = segstart + idx;
        if (SQRELU) {
          size_t ro = (size_t)p * FFDIM + colb;
#pragma unroll
          for (int j = 0; j < 4; j++) {
            float v = acc[mi][j][q];
            v = v > 0.f ? v * v : 0.f;
            h1out[ro + j * 16] = f2bf(v);
          }
        } else {
          int tok = pair_token[p];
          float wgt = pair_w[p];
          size_t ro = (size_t)tok * HDIM + colb;
#pragma unroll
          for (int j = 0; j < 4; j++)
            atomicAdd(out + ro + j * 16, acc[mi][j][q] * wgt);
        }
      }
    }
  }
}

// ---------------- launch ----------------

extern "C" void kernel_launch(void* const* d_in, const int* in_sizes, int n_in,
                              void* d_out, int out_size, void* d_ws, size_t ws_size,
                              hipStream_t stream) {
  (void)in_sizes; (void)n_in; (void)out_size; (void)ws_size;
  const float* x     = (const float*)d_in[0];
  const float* Wg    = (const float*)d_in[1];
  const float* Wfc   = (const float*)d_in[2];
  const float* Wproj = (const float*)d_in[3];
  float* out = (float*)d_out;

  char* w = (char*)d_ws;
  size_t o = 0;
  auto take = [&](size_t n) { char* p = w + o; o += (n + 255) & ~(size_t)255; return p; };
  unsigned short* xb     = (unsigned short*)take((size_t)T_TOK * HDIM * 2);
  unsigned short* WfcT   = (unsigned short*)take((size_t)NEXP * FFDIM * HDIM * 2);
  unsigned short* WprojT = (unsigned short*)take((size_t)NEXP * HDIM * FFDIM * 2);
  unsigned short* h1     = (unsigned short*)take((size_t)NPAIR * FFDIM * 2);
  int*   sel_e      = (int*)take(T_TOK * 2 * 4);
  float* sel_w      = (float*)take(T_TOK * 2 * 4);
  int*   pair_token = (int*)take(NPAIR * 4);
  float* pair_w     = (float*)take(NPAIR * 4);
  int*   counts     = (int*)take(3 * 8 * 4);
  int*   offsets    = counts + 8;
  int*   cursor     = counts + 16;

  hipMemsetAsync(out, 0, (size_t)T_TOK * HDIM * 4, stream);
  hipMemsetAsync(counts, 0, 96, stream);

  convert_x_kernel<<<T_TOK * HDIM / (256 * 8), 256, 0, stream>>>(x, xb);
  transpose_bf16_kernel<<<dim3(FFDIM / 64, HDIM / 64, NEXP), 256, 0, stream>>>(Wfc, WfcT, HDIM, FFDIM);
  transpose_bf16_kernel<<<dim3(HDIM / 64, FFDIM / 64, NEXP), 256, 0, stream>>>(Wproj, WprojT, FFDIM, HDIM);
  router_kernel<<<T_TOK / 4, 256, 0, stream>>>(x, Wg, sel_e, sel_w, counts);
  offsets_kernel<<<1, 64, 0, stream>>>(counts, offsets, cursor);
  scatter_kernel<<<T_TOK / 256, 256, 0, stream>>>(sel_e, sel_w, cursor, pair_token, pair_w);

  // GEMM1: per expert, [seg x 1024] x [1024 x 4096] -> relu^2 -> h1 (bf16)
  moe_gemm_kernel<HDIM, 1, true, true>
      <<<dim3(64, FFDIM / 128, NEXP), 256, 0, stream>>>(xb, WfcT, offsets, counts,
                                                        pair_token, pair_w, h1, nullptr);
  // GEMM2: per expert, [seg x 4096] x [4096 x 1024] -> weighted atomic combine, split-K=2
  moe_gemm_kernel<FFDIM, 2, false, false>
      <<<dim3(64, HDIM / 128, NEXP * 2), 256, 0, stream>>>(h1, WprojT, offsets, counts,
                                                           pair_token, pair_w, nullptr, out);
}

// Round 6
// 449.173 us; speedup vs baseline: 1.7050x; 1.7050x over previous
//
#include <hip/hip_runtime.h>

#define T_TOK 4096
#define HDIM  1024
#define NEXP  8
#define FFDIM 4096
#define NPAIR 8192   // T_TOK * topk
#define MAXMT 72     // max total M-tiles (128-row) across experts: 8192/128 + 8

typedef __attribute__((ext_vector_type(8))) short short8;
typedef __attribute__((ext_vector_type(8))) unsigned short ushort8;
typedef __attribute__((ext_vector_type(4))) float f32x4;

__device__ __forceinline__ unsigned short f2bf(float f) {
  unsigned int u = __float_as_uint(f);
  u += 0x7fffu + ((u >> 16) & 1u);   // RNE
  return (unsigned short)(u >> 16);
}

// global -> LDS direct copy, 16B per lane. LDS dest is wave-uniform base;
// HW writes lane l at base + l*16. Global source address is per-lane.
__device__ __forceinline__ void gload16(const void* g, const void* l) {
  __builtin_amdgcn_global_load_lds(
      (const __attribute__((address_space(1))) unsigned int*)(unsigned long long)g,
      (__attribute__((address_space(3))) unsigned int*)(unsigned int)(unsigned long long)l,
      16, 0, 0);
}

// ---------------- conversions ----------------

__global__ __launch_bounds__(256) void convert_x_kernel(
    const float* __restrict__ in, unsigned short* __restrict__ out) {
  int i = (blockIdx.x * 256 + threadIdx.x) * 8;
  float4 a = *(const float4*)(in + i);
  float4 b = *(const float4*)(in + i + 4);
  ushort8 o;
  o[0] = f2bf(a.x); o[1] = f2bf(a.y); o[2] = f2bf(a.z); o[3] = f2bf(a.w);
  o[4] = f2bf(b.x); o[5] = f2bf(b.y); o[6] = f2bf(b.z); o[7] = f2bf(b.w);
  *(ushort8*)(out + i) = o;
}

// [M][N] fp32 -> [N][M] bf16, per-expert (blockIdx.z), 64x64 tiles
__global__ __launch_bounds__(256) void transpose_bf16_kernel(
    const float* __restrict__ in, unsigned short* __restrict__ out, int M, int N) {
  in  += (size_t)blockIdx.z * M * N;
  out += (size_t)blockIdx.z * M * N;
  __shared__ unsigned short t[64][72];
  int tid = threadIdx.x;
  int r0 = blockIdx.y * 64, c0 = blockIdx.x * 64;
#pragma unroll
  for (int rr = 0; rr < 4; rr++) {
    int row = rr * 16 + (tid >> 4);
    int col = (tid & 15) * 4;
    float4 v = *(const float4*)(in + (size_t)(r0 + row) * N + c0 + col);
    t[col + 0][row] = f2bf(v.x);
    t[col + 1][row] = f2bf(v.y);
    t[col + 2][row] = f2bf(v.z);
    t[col + 3][row] = f2bf(v.w);
  }
  __syncthreads();
#pragma unroll
  for (int rr = 0; rr < 2; rr++) {
    int c = rr * 32 + (tid >> 3);
    int m0 = (tid & 7) * 8;
    ushort8 v = *(const ushort8*)&t[c][m0];
    *(ushort8*)(out + (size_t)(c0 + c) * M + r0 + m0) = v;
  }
}

// ---------------- router ----------------

__global__ __launch_bounds__(256) void router_kernel(
    const float* __restrict__ x, const float* __restrict__ wg,
    int* __restrict__ sel_e, float* __restrict__ sel_w, int* __restrict__ counts) {
  int lane = threadIdx.x & 63;
  int t = blockIdx.x * 4 + (threadIdx.x >> 6);
  const float* xr = x + (size_t)t * HDIM;
  float acc[8] = {0, 0, 0, 0, 0, 0, 0, 0};
  for (int i = 0; i < HDIM / 64; i++) {
    int h = i * 64 + lane;
    float xv = xr[h];
    float4 w0 = *(const float4*)(wg + h * 8);
    float4 w1 = *(const float4*)(wg + h * 8 + 4);
    acc[0] += xv * w0.x; acc[1] += xv * w0.y; acc[2] += xv * w0.z; acc[3] += xv * w0.w;
    acc[4] += xv * w1.x; acc[5] += xv * w1.y; acc[6] += xv * w1.z; acc[7] += xv * w1.w;
  }
#pragma unroll
  for (int off = 32; off > 0; off >>= 1) {
#pragma unroll
    for (int e = 0; e < 8; e++) acc[e] += __shfl_xor(acc[e], off, 64);
  }
  if (lane == 0) {
    int e0 = 0; float b0 = acc[0];
#pragma unroll
    for (int e = 1; e < 8; e++) if (acc[e] > b0) { b0 = acc[e]; e0 = e; }
    int e1 = -1; float b1 = -3.4e38f;
#pragma unroll
    for (int e = 0; e < 8; e++) if (e != e0 && acc[e] > b1) { b1 = acc[e]; e1 = e; }
    float q = expf(b1 - b0);                 // softmax denominator cancels in renorm
    float w0 = 1.0f / (1.0f + q);
    float w1 = q / (1.0f + q);
    sel_e[t * 2] = e0; sel_e[t * 2 + 1] = e1;
    sel_w[t * 2] = w0; sel_w[t * 2 + 1] = w1;
    atomicAdd(&counts[e0], 1);
    atomicAdd(&counts[e1], 1);
  }
}

__global__ void offsets_kernel(const int* __restrict__ counts,
                               int* __restrict__ offsets, int* __restrict__ cursor) {
  if (threadIdx.x == 0 && blockIdx.x == 0) {
    int s = 0;
    for (int e = 0; e < NEXP; e++) { offsets[e] = s; cursor[e] = s; s += counts[e]; }
  }
}

__global__ __launch_bounds__(256) void scatter_kernel(
    const int* __restrict__ sel_e, const float* __restrict__ sel_w,
    int* __restrict__ cursor, int* __restrict__ pair_token, float* __restrict__ pair_w) {
  int t = blockIdx.x * 256 + threadIdx.x;
#pragma unroll
  for (int j = 0; j < 2; j++) {
    int e = sel_e[t * 2 + j];
    int pos = atomicAdd(&cursor[e], 1);
    pair_token[pos] = t;
    pair_w[pos] = sel_w[t * 2 + j];
  }
}

// ---- expert GEMMs: 128x128 tile, BK=32, 3-slot LDS ring, single-phase tiles ----
// 4 waves (2M x 2N), wave tile 64x64, acc[4][4]. Per K-tile (round-4 ring, phases
// merged): {vmcnt(4) -> barrier -> 8 ds_read_b128 + 4 gload16 of tile t+2 ->
// barrier -> setprio(1) 16 MFMA} = 2 barriers/tile (round 4 had 5).
// vmcnt(4): tile t's 4 loads landed, t+1's 4 in flight; LAST tile drains
// vmcnt(0) (round-3 race: nothing else in flight there). 48KB -> 3 blocks/CU.
// Swizzle (round-2 proven, 0 conflicts): rows 64B = 4 chunks; LDS slot c of row
// r holds global chunk c ^ ((r>>1)&3); each consecutive-8-lane octet of a
// ds_read_b128 covers 8 distinct 16B regions (4 slots x 2 row-parity halves).
// Grid compaction: blockIdx.y = flat M-tile over all experts; block finds its
// (expert, local tile) from counts[] -> ~90% useful blocks (was ~12%).
template <int KD, int KSPL, bool GATHER, bool SQRELU>
__global__ __launch_bounds__(256, 3) void moe_gemm_kernel(
    const unsigned short* __restrict__ A0, const unsigned short* __restrict__ B0,
    const int* __restrict__ counts,
    const int* __restrict__ pair_token, const float* __restrict__ pair_w,
    unsigned short* __restrict__ h1out, float* __restrict__ out) {
  constexpr int ND = SQRELU ? FFDIM : HDIM;
  constexpr int KLEN = KD / KSPL;
  constexpr int NTILES = KLEN / 32;

  // ---- expert-tile search (wave-uniform) ----
  int by = blockIdx.y;
  int eSel = -1, tloc = 0, segstart = 0, segcnt = 0;
  {
    int cumt = 0, acc = 0;
#pragma unroll
    for (int ee = 0; ee < NEXP; ee++) {
      int c = counts[ee];
      int nt = (c + 127) >> 7;
      if (eSel < 0 && by < cumt + nt) { eSel = ee; tloc = by - cumt; segstart = acc; segcnt = c; }
      cumt += nt; acc += c;
    }
  }
  if (eSel < 0) return;

  int bx = blockIdx.x;
  int ks = blockIdx.z;
  const unsigned short* B = B0 + (size_t)eSel * ND * KD + (size_t)ks * KLEN;
  const unsigned short* Abase = A0 + (size_t)ks * KLEN;

  int tid = threadIdx.x;
  int lane = tid & 63;
  int wv = tid >> 6;       // 0..3
  int wr = wv >> 1;        // 0..1  (M)
  int wc = wv & 1;         // 0..1  (N)
  int g  = lane >> 4;      // 0..3
  int lr = lane & 15;

  // staging: inst r stages rows r*64 + (tid>>2); source k-chunk pre-swizzled
  int srow = tid >> 2;                       // 0..63
  int schunk = (tid & 3) ^ ((tid >> 3) & 3); // slot (tid&3) holds this chunk
  const unsigned short* aP[2];
  const unsigned short* bP[2];
#pragma unroll
  for (int r = 0; r < 2; r++) {
    int arow = r * 64 + srow;
    int idx = tloc * 128 + arow;
    if (idx >= segcnt) idx = segcnt - 1;     // clamp pad rows
    int p = segstart + idx;
    size_t rowoff;
    if (GATHER) rowoff = (size_t)pair_token[p] * KD;
    else        rowoff = (size_t)p * KD;
    aP[r] = Abase + rowoff + schunk * 8;
    bP[r] = B + (size_t)(bx * 128 + arow) * KD + schunk * 8;
  }

  __shared__ char lds[49152];          // 3 slots x (A 8KB + B 8KB)
  const char* ldsc = lds;
  int ldsW = wv * 1024;                // wave-uniform (lane*16 added by HW)

  // per-thread LDS read bases (within a slot)
  int swz = (g ^ ((lr >> 1) & 3)) * 16;
  int abase0 = (wr * 64 + lr) * 64 + swz;           // + mi*1024
  int bbase0 = 8192 + (wc * 64 + lr) * 64 + swz;    // + nj*1024

  f32x4 acc[4][4];
#pragma unroll
  for (int i = 0; i < 4; i++)
#pragma unroll
    for (int j = 0; j < 4; j++) acc[i][j] = (f32x4){0.f, 0.f, 0.f, 0.f};

  // prologue: stage tiles 0 and 1 into slots 0,1
#pragma unroll
  for (int t = 0; t < 2; t++) {
    int so = t * 16384;
#pragma unroll
    for (int r = 0; r < 2; r++) gload16(aP[r], ldsc + so + r * 4096 + ldsW);
#pragma unroll
    for (int r = 0; r < 2; r++) gload16(bP[r], ldsc + so + 8192 + r * 4096 + ldsW);
#pragma unroll
    for (int r = 0; r < 2; r++) { aP[r] += 32; bP[r] += 32; }
  }

  int rsOff = 0, rs2Off = 32768;
  for (int t = 0; t < NTILES; ++t) {
    // tile t landed; t+1 (if staged) stays in flight. Last iter: drain fully.
    if (t < NTILES - 1) {
      asm volatile("s_waitcnt vmcnt(4)" ::: "memory");
    } else {
      asm volatile("s_waitcnt vmcnt(0)" ::: "memory");
    }
    __builtin_amdgcn_s_barrier();
    __builtin_amdgcn_sched_barrier(0);

    short8 af[4], bf[4];
#pragma unroll
    for (int mi = 0; mi < 4; mi++)
      af[mi] = *(const short8*)(ldsc + rsOff + abase0 + mi * 1024);
#pragma unroll
    for (int nj = 0; nj < 4; nj++)
      bf[nj] = *(const short8*)(ldsc + rsOff + bbase0 + nj * 1024);
    if (t + 2 < NTILES) {               // stage tile t+2 into slot of tile t-1
      gload16(aP[0], ldsc + rs2Off + ldsW);
      gload16(aP[1], ldsc + rs2Off + 4096 + ldsW);
      gload16(bP[0], ldsc + rs2Off + 8192 + ldsW);
      gload16(bP[1], ldsc + rs2Off + 8192 + 4096 + ldsW);
#pragma unroll
      for (int r = 0; r < 2; r++) { aP[r] += 32; bP[r] += 32; }
    }
    __builtin_amdgcn_s_barrier();

    __builtin_amdgcn_s_setprio(1);
#pragma unroll
    for (int mi = 0; mi < 4; mi++)
#pragma unroll
      for (int nj = 0; nj < 4; nj++)
        acc[mi][nj] = __builtin_amdgcn_mfma_f32_16x16x32_bf16(af[mi], bf[nj], acc[mi][nj], 0, 0, 0);
    __builtin_amdgcn_s_setprio(0);

    rsOff  = (rsOff  == 32768) ? 0 : rsOff  + 16384;
    rs2Off = (rs2Off == 32768) ? 0 : rs2Off + 16384;
  }

  // ---- epilogue: C/D layout col=lane&15, row=(lane>>4)*4+q ----
  int colb = bx * 128 + wc * 64 + lr;        // + nj*16
  int rowb = tloc * 128 + wr * 64 + g * 4;   // + mi*16 + q
#pragma unroll
  for (int mi = 0; mi < 4; mi++) {
#pragma unroll
    for (int q = 0; q < 4; q++) {
      int idx = rowb + mi * 16 + q;
      if (idx < segcnt) {
        int p = segstart + idx;
        if (SQRELU) {
          size_t ro = (size_t)p * FFDIM + colb;
#pragma unroll
          for (int j = 0; j < 4; j++) {
            float v = acc[mi][j][q];
            v = v > 0.f ? v * v : 0.f;
            h1out[ro + j * 16] = f2bf(v);
          }
        } else {
          int tok = pair_token[p];
          float wgt = pair_w[p];
          size_t ro = (size_t)tok * HDIM + colb;
#pragma unroll
          for (int j = 0; j < 4; j++)
            atomicAdd(out + ro + j * 16, acc[mi][j][q] * wgt);
        }
      }
    }
  }
}

// ---------------- launch ----------------

extern "C" void kernel_launch(void* const* d_in, const int* in_sizes, int n_in,
                              void* d_out, int out_size, void* d_ws, size_t ws_size,
                              hipStream_t stream) {
  (void)in_sizes; (void)n_in; (void)out_size; (void)ws_size;
  const float* x     = (const float*)d_in[0];
  const float* Wg    = (const float*)d_in[1];
  const float* Wfc   = (const float*)d_in[2];
  const float* Wproj = (const float*)d_in[3];
  float* out = (float*)d_out;

  char* w = (char*)d_ws;
  size_t o = 0;
  auto take = [&](size_t n) { char* p = w + o; o += (n + 255) & ~(size_t)255; return p; };
  unsigned short* xb     = (unsigned short*)take((size_t)T_TOK * HDIM * 2);
  unsigned short* WfcT   = (unsigned short*)take((size_t)NEXP * FFDIM * HDIM * 2);
  unsigned short* WprojT = (unsigned short*)take((size_t)NEXP * HDIM * FFDIM * 2);
  unsigned short* h1     = (unsigned short*)take((size_t)NPAIR * FFDIM * 2);
  int*   sel_e      = (int*)take(T_TOK * 2 * 4);
  float* sel_w      = (float*)take(T_TOK * 2 * 4);
  int*   pair_token = (int*)take(NPAIR * 4);
  float* pair_w     = (float*)take(NPAIR * 4);
  int*   counts     = (int*)take(3 * 8 * 4);
  int*   offsets    = counts + 8;
  int*   cursor     = counts + 16;

  hipMemsetAsync(out, 0, (size_t)T_TOK * HDIM * 4, stream);
  hipMemsetAsync(counts, 0, 96, stream);

  convert_x_kernel<<<T_TOK * HDIM / (256 * 8), 256, 0, stream>>>(x, xb);
  transpose_bf16_kernel<<<dim3(FFDIM / 64, HDIM / 64, NEXP), 256, 0, stream>>>(Wfc, WfcT, HDIM, FFDIM);
  transpose_bf16_kernel<<<dim3(HDIM / 64, FFDIM / 64, NEXP), 256, 0, stream>>>(Wproj, WprojT, FFDIM, HDIM);
  router_kernel<<<T_TOK / 4, 256, 0, stream>>>(x, Wg, sel_e, sel_w, counts);
  offsets_kernel<<<1, 64, 0, stream>>>(counts, offsets, cursor);
  scatter_kernel<<<T_TOK / 256, 256, 0, stream>>>(sel_e, sel_w, cursor, pair_token, pair_w);

  // GEMM1: per expert, [seg x 1024] x [1024 x 4096] -> relu^2 -> h1 (bf16)
  moe_gemm_kernel<HDIM, 1, true, true>
      <<<dim3(FFDIM / 128, MAXMT, 1), 256, 0, stream>>>(xb, WfcT, counts,
                                                        pair_token, pair_w, h1, nullptr);
  // GEMM2: per expert, [seg x 4096] x [4096 x 1024] -> weighted atomic combine, split-K=2
  moe_gemm_kernel<FFDIM, 2, false, false>
      <<<dim3(HDIM / 128, MAXMT, 2), 256, 0, stream>>>(h1, WprojT, counts,
                                                       pair_token, pair_w, nullptr, out);
}